// Round 15
// baseline (253.575 us; speedup 1.0000x reference)
//
#include <hip/hip_runtime.h>
#include <hip/hip_bf16.h>
#include <stdint.h>

// MQA: B=2, S=2048, D=1024, H=16, DH=64. Inputs f32, OUTPUT f32.
// r15: 64 q-rows per wave (dual Q fragments per K/V load) -> K/V L1 traffic
// per unit compute halved. r14 showed occupancy buys ~nothing (L1/TA-delivery
// bound on K/V: ~1.6GB through L1 ~= whole attn time). Packed fragments (r12),
// single-acc QK chain (r13), split-KV x4 + merge (r14) retained.

#define B_   2
#define S_   2048
#define D_   1024
#define H_   16
#define DH_  64
#define MTOT (B_ * S_)  // 4096
#define NSPL 4

typedef short bf16x8 __attribute__((ext_vector_type(8)));
typedef float f32x4 __attribute__((ext_vector_type(4)));
typedef float f32x16 __attribute__((ext_vector_type(16)));
typedef short short4v __attribute__((ext_vector_type(4)));
typedef unsigned uint4v __attribute__((ext_vector_type(4)));

__device__ __forceinline__ short f2bf(float f) {  // RNE f32->bf16
  unsigned u = __float_as_uint(f);
  u += 0x7FFF + ((u >> 16) & 1);
  return (short)(u >> 16);
}
__device__ __forceinline__ float bf2f(short h) {
  return __uint_as_float(((unsigned)(unsigned short)h) << 16);
}
struct bfpair { short hi, lo; };
__device__ __forceinline__ bfpair split2(float x) {
  bfpair p;
  p.hi = f2bf(x);
  p.lo = f2bf(x - bf2f(p.hi));
  return p;
}
__device__ __forceinline__ unsigned cvtpk(float lo, float hi) {
  unsigned r;
  asm("v_cvt_pk_bf16_f32 %0, %1, %2" : "=v"(r) : "v"(lo), "v"(hi));
  return r;
}

__device__ __forceinline__ void glds16(const void* g, void* l) {
  __builtin_amdgcn_global_load_lds((const __attribute__((address_space(1))) void*)g,
                                   (__attribute__((address_space(3))) void*)l, 16, 0, 0);
}

// ---------------- f32 -> bf16 convert, hi/lo split where needed ----------------
__global__ __launch_bounds__(256) void cvt_split(
    const float* __restrict__ q, const float* __restrict__ k, const float* __restrict__ v,
    const float* __restrict__ wq, const float* __restrict__ wk, const float* __restrict__ wv,
    const float* __restrict__ wo,
    short* qhi, short* qlo, short* khi, short* klo, short* vb,
    short* wqh, short* wql, short* wkh, short* wkl, short* wvb,
    short* woh, short* wol) {
  const int U0 = 1048576, U1 = 2097152, U2 = 3145728, U3 = 3407872,
            U4 = 3424256, U5 = 3440640, U6 = 3702784;
  for (int u = blockIdx.x * blockDim.x + threadIdx.x; u < U6; u += gridDim.x * blockDim.x) {
    const float* s; short* dh; short* dl; int r;
    if (u < U0)      { s = q;  dh = qhi; dl = qlo; r = u; }
    else if (u < U1) { s = k;  dh = khi; dl = klo; r = u - U0; }
    else if (u < U2) { s = v;  dh = vb;  dl = nullptr; r = u - U1; }
    else if (u < U3) { s = wq; dh = wqh; dl = wql; r = u - U2; }
    else if (u < U4) { s = wk; dh = wkh; dl = wkl; r = u - U3; }
    else if (u < U5) { s = wv; dh = wvb; dl = nullptr; r = u - U4; }
    else             { s = wo; dh = woh; dl = wol; r = u - U5; }
    float4 x = *(const float4*)(s + (size_t)r * 4);
    bfpair p0 = split2(x.x), p1 = split2(x.y), p2 = split2(x.z), p3 = split2(x.w);
    short4v yh, yl;
    yh.x = p0.hi; yh.y = p1.hi; yh.z = p2.hi; yh.w = p3.hi;
    yl.x = p0.lo; yl.y = p1.lo; yl.z = p2.lo; yl.w = p3.lo;
    *(short4v*)(dh + (size_t)r * 4) = yh;
    if (dl) *(short4v*)(dl + (size_t)r * 4) = yl;
  }
}

// ---------------- GEMM  C = (Ah+Al) * (Bh+Bl)^T, f32 acc ----------------
// MODE 0: split pair row-major. MODE 3: f32 row-major.
// MODE 4: K-fragment-packed split pair  PK[tok>>5][dh>>4][(tok&31)+32*((dh>>3)&1)][dh&7]
// MODE 5: V-fragment-packed single bf16 PV[tok>>5][dh>>5][(tok>>4)&1][(dh&31)+32*((tok>>3)&1)][tok&7]
template <int NPROD, int MODE>
__global__ __launch_bounds__(256) void gemm3(
    const short* __restrict__ Ah, const short* __restrict__ Al,
    const short* __restrict__ Bh, const short* __restrict__ Bl,
    short* __restrict__ Ch, short* __restrict__ Cl, float* __restrict__ Cf,
    int K, int lda, int ldb, int ldc, float alpha) {
  __shared__ alignas(16) short Ash[4096], Asl[4096], Bsh[4096], Bsl[4096];
  const int tid = threadIdx.x;
  const int lane = tid & 63, w = tid >> 6;
  const int c = lane & 15, g = lane >> 4;
  const int wm = w >> 1, wn = w & 1;
  const int bm = blockIdx.x * 64, bn = blockIdx.y * 64;
  const int sr = lane >> 3;
  const int scs = ((lane & 7) ^ sr) * 8;

  f32x4 acc[2][2] = {};
  for (int k0 = 0; k0 < K; k0 += 64) {
    glds16(Ah + (size_t)(bm + w * 8 + sr) * lda + k0 + scs,      Ash + w * 512);
    glds16(Ah + (size_t)(bm + 32 + w * 8 + sr) * lda + k0 + scs, Ash + 2048 + w * 512);
    glds16(Bh + (size_t)(bn + w * 8 + sr) * ldb + k0 + scs,      Bsh + w * 512);
    glds16(Bh + (size_t)(bn + 32 + w * 8 + sr) * ldb + k0 + scs, Bsh + 2048 + w * 512);
    if constexpr (NPROD == 3) {
      glds16(Al + (size_t)(bm + w * 8 + sr) * lda + k0 + scs,      Asl + w * 512);
      glds16(Al + (size_t)(bm + 32 + w * 8 + sr) * lda + k0 + scs, Asl + 2048 + w * 512);
      glds16(Bl + (size_t)(bn + w * 8 + sr) * ldb + k0 + scs,      Bsl + w * 512);
      glds16(Bl + (size_t)(bn + 32 + w * 8 + sr) * ldb + k0 + scs, Bsl + 2048 + w * 512);
    }
    __syncthreads();
#pragma unroll
    for (int kk = 0; kk < 2; ++kk) {
      bf16x8 ah[2], bh[2], al[2], bl[2];
#pragma unroll
      for (int mt = 0; mt < 2; ++mt) {
        int row = wm * 32 + mt * 16 + c;
        int so = row * 64 + (((kk * 4 + g) ^ (row & 7)) * 8);
        ah[mt] = *(const bf16x8*)(Ash + so);
        if constexpr (NPROD == 3) al[mt] = *(const bf16x8*)(Asl + so);
      }
#pragma unroll
      for (int nt = 0; nt < 2; ++nt) {
        int row = wn * 32 + nt * 16 + c;
        int so = row * 64 + (((kk * 4 + g) ^ (row & 7)) * 8);
        bh[nt] = *(const bf16x8*)(Bsh + so);
        if constexpr (NPROD == 3) bl[nt] = *(const bf16x8*)(Bsl + so);
      }
#pragma unroll
      for (int mt = 0; mt < 2; ++mt)
#pragma unroll
        for (int nt = 0; nt < 2; ++nt) {
          acc[mt][nt] = __builtin_amdgcn_mfma_f32_16x16x32_bf16(ah[mt], bh[nt], acc[mt][nt], 0, 0, 0);
          if constexpr (NPROD == 3) {
            acc[mt][nt] = __builtin_amdgcn_mfma_f32_16x16x32_bf16(ah[mt], bl[nt], acc[mt][nt], 0, 0, 0);
            acc[mt][nt] = __builtin_amdgcn_mfma_f32_16x16x32_bf16(al[mt], bh[nt], acc[mt][nt], 0, 0, 0);
          }
        }
    }
    __syncthreads();
  }
#pragma unroll
  for (int mt = 0; mt < 2; ++mt) {
#pragma unroll
    for (int nt = 0; nt < 2; ++nt) {
#pragma unroll
      for (int r = 0; r < 4; ++r) {
        int m = bm + wm * 32 + mt * 16 + g * 4 + r;   // row (token)
        int n = bn + wn * 32 + nt * 16 + c;           // col (dh / N)
        float val = acc[mt][nt][r] * alpha;
        if constexpr (MODE == 0) {
          bfpair pr = split2(val);
          Ch[(size_t)m * ldc + n] = pr.hi;
          Cl[(size_t)m * ldc + n] = pr.lo;
        } else if constexpr (MODE == 3) {
          Cf[(size_t)m * ldc + n] = val;
        } else if constexpr (MODE == 4) {
          size_t off = (((size_t)(m >> 5) * 4 + (n >> 4)) * 64 +
                        ((m & 31) + 32 * ((n >> 3) & 1))) * 8 + (n & 7);
          bfpair pr = split2(val);
          Ch[off] = pr.hi;
          Cl[off] = pr.lo;
        } else {  // MODE 5
          size_t off = ((((size_t)(m >> 5) * 2 + (n >> 5)) * 2 + ((m >> 4) & 1)) * 64 +
                        ((n & 31) + 32 * ((m >> 3) & 1))) * 8 + (m & 7);
          Ch[off] = f2bf(val);
        }
      }
    }
  }
}

// ---------------- flash MQA attention v9: 64 q-rows/wave, dual Q pipelines --------
// grid (S/256, H, B*NSPL), 256 thr = 4 waves; wave w owns 64 q-rows
// (q0 = qt*256 + w*64; block A = q0+j, block B = q0+32+j). One K/V load feeds
// both pipelines -> K/V L1 traffic per q halved vs r14.
__global__ __launch_bounds__(256) void mqa_attn(
    const short* __restrict__ qph, const short* __restrict__ qpl,
    const short* __restrict__ pkh, const short* __restrict__ pkl,
    const short* __restrict__ pv, short* __restrict__ pO, float* __restrict__ pML) {
  const int tid = threadIdx.x;
  const int lane = tid & 63, w = tid >> 6;
  const int j = lane & 31, b5 = lane >> 5;
  const int qt = blockIdx.x, h = blockIdx.y;
  const int b = blockIdx.z >> 2, sp = blockIdx.z & 3;
  const int q0 = qt * 256 + w * 64;
  const int kvbeg = sp * (S_ / NSPL), kvend = kvbeg + S_ / NSPL;

  const size_t qbaseA = (size_t)(b * S_ + q0 + j) * D_ + h * DH_ + b5 * 8;
  const size_t qbaseB = qbaseA + (size_t)32 * D_;
  bf16x8 qhA[4], qlA[4], qhB[4], qlB[4];
#pragma unroll
  for (int m = 0; m < 4; ++m) {
    qhA[m] = *(const bf16x8*)(qph + qbaseA + m * 16);
    qlA[m] = *(const bf16x8*)(qpl + qbaseA + m * 16);
    qhB[m] = *(const bf16x8*)(qph + qbaseB + m * 16);
    qlB[m] = *(const bf16x8*)(qpl + qbaseB + m * 16);
  }

  float mrowA = -1.0e30f, lrowA = 0.f, mrowB = -1.0e30f, lrowB = 0.f;
  f32x16 oA0 = {}, oA1 = {}, oB0 = {}, oB1 = {};

  for (int kv0 = kvbeg; kv0 < kvend; kv0 += 32) {
    const size_t tg = (size_t)((b * S_ + kv0) >> 5);
    // ---- K fragments: packed, lane-contiguous (shared by both q-blocks) ----
    const short* kb = pkh + tg * 2048 + lane * 8;
    const short* kb2 = pkl + tg * 2048 + lane * 8;
    bf16x8 kh[4], kl[4];
#pragma unroll
    for (int m = 0; m < 4; ++m) {
      kh[m] = *(const bf16x8*)(kb + m * 512);
      kl[m] = *(const bf16x8*)(kb2 + m * 512);
    }
    // ---- scores A and B: 12 MFMAs each, single accumulator ----
    f32x16 sA = {}, sB = {};
#pragma unroll
    for (int m = 0; m < 4; ++m)
      sA = __builtin_amdgcn_mfma_f32_32x32x16_bf16(kh[m], qhA[m], sA, 0, 0, 0);
#pragma unroll
    for (int m = 0; m < 4; ++m)
      sA = __builtin_amdgcn_mfma_f32_32x32x16_bf16(kl[m], qhA[m], sA, 0, 0, 0);
#pragma unroll
    for (int m = 0; m < 4; ++m)
      sA = __builtin_amdgcn_mfma_f32_32x32x16_bf16(kh[m], qlA[m], sA, 0, 0, 0);
#pragma unroll
    for (int m = 0; m < 4; ++m)
      sB = __builtin_amdgcn_mfma_f32_32x32x16_bf16(kh[m], qhB[m], sB, 0, 0, 0);
#pragma unroll
    for (int m = 0; m < 4; ++m)
      sB = __builtin_amdgcn_mfma_f32_32x32x16_bf16(kl[m], qhB[m], sB, 0, 0, 0);
#pragma unroll
    for (int m = 0; m < 4; ++m)
      sB = __builtin_amdgcn_mfma_f32_32x32x16_bf16(kh[m], qlB[m], sB, 0, 0, 0);
    // ---- softmax A (defer-max, THR=8, log2 domain) ----
    float mxA = sA[0];
#pragma unroll
    for (int r = 1; r < 16; ++r) mxA = fmaxf(mxA, sA[r]);
    mxA = fmaxf(mxA, __shfl_xor(mxA, 32));
    if (!__all(mxA - mrowA <= 8.0f)) {
      float mn = fmaxf(mrowA, mxA);
      float scale = exp2f(mrowA - mn);
      mrowA = mn;
      lrowA *= scale;
      oA0 *= scale;
      oA1 *= scale;
    }
    float pA[16];
#pragma unroll
    for (int r = 0; r < 16; ++r) pA[r] = exp2f(sA[r] - mrowA);
    float rsA = (((pA[0] + pA[1]) + (pA[2] + pA[3])) + ((pA[4] + pA[5]) + (pA[6] + pA[7]))) +
                (((pA[8] + pA[9]) + (pA[10] + pA[11])) + ((pA[12] + pA[13]) + (pA[14] + pA[15])));
    rsA += __shfl_xor(rsA, 32);
    lrowA += rsA;
    // ---- softmax B ----
    float mxB = sB[0];
#pragma unroll
    for (int r = 1; r < 16; ++r) mxB = fmaxf(mxB, sB[r]);
    mxB = fmaxf(mxB, __shfl_xor(mxB, 32));
    if (!__all(mxB - mrowB <= 8.0f)) {
      float mn = fmaxf(mrowB, mxB);
      float scale = exp2f(mrowB - mn);
      mrowB = mn;
      lrowB *= scale;
      oB0 *= scale;
      oB1 *= scale;
    }
    float pB[16];
#pragma unroll
    for (int r = 0; r < 16; ++r) pB[r] = exp2f(sB[r] - mrowB);
    float rsB = (((pB[0] + pB[1]) + (pB[2] + pB[3])) + ((pB[4] + pB[5]) + (pB[6] + pB[7]))) +
                (((pB[8] + pB[9]) + (pB[10] + pB[11])) + ((pB[12] + pB[13]) + (pB[14] + pB[15])));
    rsB += __shfl_xor(rsB, 32);
    lrowB += rsB;
    // ---- P^T fragments (A then B) via cvt_pk + permlane32_swap ----
    auto a0 = __builtin_amdgcn_permlane32_swap(cvtpk(pA[0], pA[1]),   cvtpk(pA[4], pA[5]),   false, false);
    auto a1 = __builtin_amdgcn_permlane32_swap(cvtpk(pA[2], pA[3]),   cvtpk(pA[6], pA[7]),   false, false);
    auto a2 = __builtin_amdgcn_permlane32_swap(cvtpk(pA[8], pA[9]),   cvtpk(pA[12], pA[13]), false, false);
    auto a3 = __builtin_amdgcn_permlane32_swap(cvtpk(pA[10], pA[11]), cvtpk(pA[14], pA[15]), false, false);
    union { uint4v u; bf16x8 v; } paA0, paA1, paB0, paB1;
    paA0.u = (uint4v){a0[0], a1[0], a0[1], a1[1]};
    paA1.u = (uint4v){a2[0], a3[0], a2[1], a3[1]};
    auto b0 = __builtin_amdgcn_permlane32_swap(cvtpk(pB[0], pB[1]),   cvtpk(pB[4], pB[5]),   false, false);
    auto b1 = __builtin_amdgcn_permlane32_swap(cvtpk(pB[2], pB[3]),   cvtpk(pB[6], pB[7]),   false, false);
    auto b2 = __builtin_amdgcn_permlane32_swap(cvtpk(pB[8], pB[9]),   cvtpk(pB[12], pB[13]), false, false);
    auto b3 = __builtin_amdgcn_permlane32_swap(cvtpk(pB[10], pB[11]), cvtpk(pB[14], pB[15]), false, false);
    paB0.u = (uint4v){b0[0], b1[0], b0[1], b1[1]};
    paB1.u = (uint4v){b2[0], b3[0], b2[1], b3[1]};
    // ---- O^T += V^T x P^T : one V load feeds both pipelines ----
    const short* vbp = pv + tg * 2048 + lane * 8;
    bf16x8 va00 = *(const bf16x8*)(vbp);
    bf16x8 va01 = *(const bf16x8*)(vbp + 512);
    bf16x8 va10 = *(const bf16x8*)(vbp + 1024);
    bf16x8 va11 = *(const bf16x8*)(vbp + 1536);
    oA0 = __builtin_amdgcn_mfma_f32_32x32x16_bf16(va00, paA0.v, oA0, 0, 0, 0);
    oA0 = __builtin_amdgcn_mfma_f32_32x32x16_bf16(va01, paA1.v, oA0, 0, 0, 0);
    oA1 = __builtin_amdgcn_mfma_f32_32x32x16_bf16(va10, paA0.v, oA1, 0, 0, 0);
    oA1 = __builtin_amdgcn_mfma_f32_32x32x16_bf16(va11, paA1.v, oA1, 0, 0, 0);
    oB0 = __builtin_amdgcn_mfma_f32_32x32x16_bf16(va00, paB0.v, oB0, 0, 0, 0);
    oB0 = __builtin_amdgcn_mfma_f32_32x32x16_bf16(va01, paB1.v, oB0, 0, 0, 0);
    oB1 = __builtin_amdgcn_mfma_f32_32x32x16_bf16(va10, paB0.v, oB1, 0, 0, 0);
    oB1 = __builtin_amdgcn_mfma_f32_32x32x16_bf16(va11, paB1.v, oB1, 0, 0, 0);
  }
  // ---- epilogue: unnormalized O^T partials + (m,l) for both q-blocks ----
  const size_t tokA = (size_t)(b * S_ + q0 + j);
  const size_t obaseA = ((size_t)sp * MTOT + tokA) * D_ + h * DH_;
  const size_t obaseB = obaseA + (size_t)32 * D_;
#pragma unroll
  for (int r = 0; r < 16; ++r) {
    int dh0 = (r & 3) + 8 * (r >> 2) + 4 * b5;
    pO[obaseA + dh0] = f2bf(oA0[r]);
    pO[obaseA + 32 + dh0] = f2bf(oA1[r]);
    pO[obaseB + dh0] = f2bf(oB0[r]);
    pO[obaseB + 32 + dh0] = f2bf(oB1[r]);
  }
  if (b5 == 0) {
    size_t mbA = (((size_t)sp * MTOT + tokA) * H_ + h) * 2;
    size_t mbB = (((size_t)sp * MTOT + tokA + 32) * H_ + h) * 2;
    pML[mbA] = mrowA;
    pML[mbA + 1] = lrowA;
    pML[mbB] = mrowB;
    pML[mbB + 1] = lrowB;
  }
}

// ---------------- merge NSPL KV-split partials -> split bf16 ao ----------------
__global__ __launch_bounds__(256) void attn_merge(
    const short* __restrict__ pO, const float* __restrict__ pML,
    short* __restrict__ aoh, short* __restrict__ aol) {
  int qd = blockIdx.x * 256 + threadIdx.x;
  size_t idx = (size_t)qd * 4;
  int tok = (int)(idx >> 10);
  int h = (int)((idx >> 6) & 15);
  float ms[NSPL], ls[NSPL], mm = -1.0e30f;
#pragma unroll
  for (int s = 0; s < NSPL; ++s) {
    size_t mb = (((size_t)s * MTOT + tok) * H_ + h) * 2;
    ms[s] = pML[mb];
    ls[s] = pML[mb + 1];
    mm = fmaxf(mm, ms[s]);
  }
  float num[4] = {}, den = 0.f;
#pragma unroll
  for (int s = 0; s < NSPL; ++s) {
    float e = exp2f(ms[s] - mm);
    den += ls[s] * e;
    short4v o4 = *(const short4v*)(pO + (size_t)s * MTOT * D_ + idx);
    num[0] += bf2f(o4.x) * e;
    num[1] += bf2f(o4.y) * e;
    num[2] += bf2f(o4.z) * e;
    num[3] += bf2f(o4.w) * e;
  }
  float inv = 1.0f / den;
  short4v yh, yl;
  bfpair p0 = split2(num[0] * inv), p1 = split2(num[1] * inv),
         p2 = split2(num[2] * inv), p3 = split2(num[3] * inv);
  yh.x = p0.hi; yh.y = p1.hi; yh.z = p2.hi; yh.w = p3.hi;
  yl.x = p0.lo; yl.y = p1.lo; yl.z = p2.lo; yl.w = p3.lo;
  *(short4v*)(aoh + idx) = yh;
  *(short4v*)(aol + idx) = yl;
}

// ---------------- launch ----------------
extern "C" void kernel_launch(void* const* d_in, const int* in_sizes, int n_in,
                              void* d_out, int out_size, void* d_ws, size_t ws_size,
                              hipStream_t stream) {
  const float* q  = (const float*)d_in[0];
  const float* k  = (const float*)d_in[1];
  const float* v  = (const float*)d_in[2];
  const float* wq = (const float*)d_in[3];
  const float* wk = (const float*)d_in[4];
  const float* wv = (const float*)d_in[5];
  const float* wo = (const float*)d_in[6];

  short* p = (short*)d_ws;
  short* qhi = p; p += 4194304;   // dead after Q-proj -> pO splits 0,1
  short* qlo = p; p += 4194304;
  short* khi = p; p += 4194304;   // dead after K-proj -> pO splits 2,3
  short* klo = p; p += 4194304;
  short* vb  = p; p += 4194304;   // dead after V-proj -> pML
  short* wqh = p; p += 1048576;
  short* wql = p; p += 1048576;
  short* wkh = p; p += 65536;
  short* wkl = p; p += 65536;
  short* wvb = p; p += 65536;
  short* woh = p; p += 1048576;
  short* wol = p; p += 1048576;
  short* qph = p; p += 4194304;   // dead after attn -> aoh
  short* qpl = p; p += 4194304;   // dead after attn -> aol
  short* pkh = p; p += 524288;    // packed K hi [128 tiles][4][64][8]
  short* pkl = p; p += 524288;    // packed K lo
  short* pv  = p; p += 524288;    // packed V^T [128 tiles][2][2][64][8]
  short* pO  = qhi;               // [NSPL][4096][1024] bf16 = 33.6 MB
  float* pML = (float*)vb;        // [NSPL][4096][16][2] f32 = 2 MB
  short* aoh = qph;               // merge runs after attn reads qph/qpl
  short* aol = qpl;

  cvt_split<<<dim3(2048), dim3(256), 0, stream>>>(q, k, v, wq, wk, wv, wo,
      qhi, qlo, khi, klo, vb, wqh, wql, wkh, wkl, wvb, woh, wol);
  // qp = q @ wq^T * (0.125 * log2e)  -> exp2-domain scores
  gemm3<3, 0><<<dim3(64, 16), dim3(256), 0, stream>>>(qhi, qlo, wqh, wql, qph, qpl,
      nullptr, 1024, 1024, 1024, 1024, 0.125f * 1.44269504f);
  // kp -> packed fragment layout (split)
  gemm3<3, 4><<<dim3(64, 1), dim3(256), 0, stream>>>(khi, klo, wkh, wkl, pkh, pkl,
      nullptr, 1024, 1024, 1024, 64, 1.0f);
  // vp -> packed V^T fragment layout
  gemm3<1, 5><<<dim3(64, 1), dim3(256), 0, stream>>>(vb, nullptr, wvb, nullptr, pv,
      nullptr, nullptr, 1024, 1024, 1024, 64, 1.0f);
  mqa_attn<<<dim3(S_ / 256, 16, B_ * NSPL), dim3(256), 0, stream>>>(
      qph, qpl, pkh, pkl, pv, pO, pML);
  attn_merge<<<dim3(MTOT * D_ / 4 / 256), dim3(256), 0, stream>>>(pO, pML, aoh, aol);
  gemm3<3, 3><<<dim3(64, 16), dim3(256), 0, stream>>>(aoh, aol, woh, wol, nullptr,
      nullptr, (float*)d_out, 1024, 1024, 1024, 1024, 1.0f);
}

// Round 16
// 203.133 us; speedup vs baseline: 1.2483x; 1.2483x over previous
//
#include <hip/hip_runtime.h>
#include <hip/hip_bf16.h>
#include <stdint.h>

// MQA: B=2, S=2048, D=1024, H=16, DH=64. Inputs f32, OUTPUT f32.
// r16: attn reverted to r14 (32q/wave — r15's 64q halved occupancy, regressed).
// Out-proj downgraded to SINGLE bf16 (NPROD=1): post-softmax path tolerates
// bf16 (err sigma~1.4 << 311); saves 2/3 of out-proj work. Split precision
// kept on the score path only (q,k projections).

#define B_   2
#define S_   2048
#define D_   1024
#define H_   16
#define DH_  64
#define MTOT (B_ * S_)  // 4096
#define NSPL 4

typedef short bf16x8 __attribute__((ext_vector_type(8)));
typedef float f32x4 __attribute__((ext_vector_type(4)));
typedef float f32x16 __attribute__((ext_vector_type(16)));
typedef short short4v __attribute__((ext_vector_type(4)));
typedef unsigned uint4v __attribute__((ext_vector_type(4)));

__device__ __forceinline__ short f2bf(float f) {  // RNE f32->bf16
  unsigned u = __float_as_uint(f);
  u += 0x7FFF + ((u >> 16) & 1);
  return (short)(u >> 16);
}
__device__ __forceinline__ float bf2f(short h) {
  return __uint_as_float(((unsigned)(unsigned short)h) << 16);
}
struct bfpair { short hi, lo; };
__device__ __forceinline__ bfpair split2(float x) {
  bfpair p;
  p.hi = f2bf(x);
  p.lo = f2bf(x - bf2f(p.hi));
  return p;
}
__device__ __forceinline__ unsigned cvtpk(float lo, float hi) {
  unsigned r;
  asm("v_cvt_pk_bf16_f32 %0, %1, %2" : "=v"(r) : "v"(lo), "v"(hi));
  return r;
}

__device__ __forceinline__ void glds16(const void* g, void* l) {
  __builtin_amdgcn_global_load_lds((const __attribute__((address_space(1))) void*)g,
                                   (__attribute__((address_space(3))) void*)l, 16, 0, 0);
}

// ---------------- f32 -> bf16 convert; hi/lo split for q,k,wq,wk only ----------------
__global__ __launch_bounds__(256) void cvt_split(
    const float* __restrict__ q, const float* __restrict__ k, const float* __restrict__ v,
    const float* __restrict__ wq, const float* __restrict__ wk, const float* __restrict__ wv,
    const float* __restrict__ wo,
    short* qhi, short* qlo, short* khi, short* klo, short* vb,
    short* wqh, short* wql, short* wkh, short* wkl, short* wvb, short* wob) {
  const int U0 = 1048576, U1 = 2097152, U2 = 3145728, U3 = 3407872,
            U4 = 3424256, U5 = 3440640, U6 = 3702784;
  for (int u = blockIdx.x * blockDim.x + threadIdx.x; u < U6; u += gridDim.x * blockDim.x) {
    const float* s; short* dh; short* dl; int r;
    if (u < U0)      { s = q;  dh = qhi; dl = qlo; r = u; }
    else if (u < U1) { s = k;  dh = khi; dl = klo; r = u - U0; }
    else if (u < U2) { s = v;  dh = vb;  dl = nullptr; r = u - U1; }
    else if (u < U3) { s = wq; dh = wqh; dl = wql; r = u - U2; }
    else if (u < U4) { s = wk; dh = wkh; dl = wkl; r = u - U3; }
    else if (u < U5) { s = wv; dh = wvb; dl = nullptr; r = u - U4; }
    else             { s = wo; dh = wob; dl = nullptr; r = u - U5; }
    float4 x = *(const float4*)(s + (size_t)r * 4);
    bfpair p0 = split2(x.x), p1 = split2(x.y), p2 = split2(x.z), p3 = split2(x.w);
    short4v yh, yl;
    yh.x = p0.hi; yh.y = p1.hi; yh.z = p2.hi; yh.w = p3.hi;
    yl.x = p0.lo; yl.y = p1.lo; yl.z = p2.lo; yl.w = p3.lo;
    *(short4v*)(dh + (size_t)r * 4) = yh;
    if (dl) *(short4v*)(dl + (size_t)r * 4) = yl;
  }
}

// ---------------- GEMM  C = (Ah+Al) * (Bh+Bl)^T, f32 acc ----------------
// MODE 0: split pair row-major. MODE 3: f32 row-major.
// MODE 4: K-fragment-packed split pair  PK[tok>>5][dh>>4][(tok&31)+32*((dh>>3)&1)][dh&7]
// MODE 5: V-fragment-packed single bf16 PV[tok>>5][dh>>5][(tok>>4)&1][(dh&31)+32*((tok>>3)&1)][tok&7]
template <int NPROD, int MODE>
__global__ __launch_bounds__(256) void gemm3(
    const short* __restrict__ Ah, const short* __restrict__ Al,
    const short* __restrict__ Bh, const short* __restrict__ Bl,
    short* __restrict__ Ch, short* __restrict__ Cl, float* __restrict__ Cf,
    int K, int lda, int ldb, int ldc, float alpha) {
  __shared__ alignas(16) short Ash[4096], Asl[4096], Bsh[4096], Bsl[4096];
  const int tid = threadIdx.x;
  const int lane = tid & 63, w = tid >> 6;
  const int c = lane & 15, g = lane >> 4;
  const int wm = w >> 1, wn = w & 1;
  const int bm = blockIdx.x * 64, bn = blockIdx.y * 64;
  const int sr = lane >> 3;
  const int scs = ((lane & 7) ^ sr) * 8;

  f32x4 acc[2][2] = {};
  for (int k0 = 0; k0 < K; k0 += 64) {
    glds16(Ah + (size_t)(bm + w * 8 + sr) * lda + k0 + scs,      Ash + w * 512);
    glds16(Ah + (size_t)(bm + 32 + w * 8 + sr) * lda + k0 + scs, Ash + 2048 + w * 512);
    glds16(Bh + (size_t)(bn + w * 8 + sr) * ldb + k0 + scs,      Bsh + w * 512);
    glds16(Bh + (size_t)(bn + 32 + w * 8 + sr) * ldb + k0 + scs, Bsh + 2048 + w * 512);
    if constexpr (NPROD == 3) {
      glds16(Al + (size_t)(bm + w * 8 + sr) * lda + k0 + scs,      Asl + w * 512);
      glds16(Al + (size_t)(bm + 32 + w * 8 + sr) * lda + k0 + scs, Asl + 2048 + w * 512);
      glds16(Bl + (size_t)(bn + w * 8 + sr) * ldb + k0 + scs,      Bsl + w * 512);
      glds16(Bl + (size_t)(bn + 32 + w * 8 + sr) * ldb + k0 + scs, Bsl + 2048 + w * 512);
    }
    __syncthreads();
#pragma unroll
    for (int kk = 0; kk < 2; ++kk) {
      bf16x8 ah[2], bh[2], al[2], bl[2];
#pragma unroll
      for (int mt = 0; mt < 2; ++mt) {
        int row = wm * 32 + mt * 16 + c;
        int so = row * 64 + (((kk * 4 + g) ^ (row & 7)) * 8);
        ah[mt] = *(const bf16x8*)(Ash + so);
        if constexpr (NPROD == 3) al[mt] = *(const bf16x8*)(Asl + so);
      }
#pragma unroll
      for (int nt = 0; nt < 2; ++nt) {
        int row = wn * 32 + nt * 16 + c;
        int so = row * 64 + (((kk * 4 + g) ^ (row & 7)) * 8);
        bh[nt] = *(const bf16x8*)(Bsh + so);
        if constexpr (NPROD == 3) bl[nt] = *(const bf16x8*)(Bsl + so);
      }
#pragma unroll
      for (int mt = 0; mt < 2; ++mt)
#pragma unroll
        for (int nt = 0; nt < 2; ++nt) {
          acc[mt][nt] = __builtin_amdgcn_mfma_f32_16x16x32_bf16(ah[mt], bh[nt], acc[mt][nt], 0, 0, 0);
          if constexpr (NPROD == 3) {
            acc[mt][nt] = __builtin_amdgcn_mfma_f32_16x16x32_bf16(ah[mt], bl[nt], acc[mt][nt], 0, 0, 0);
            acc[mt][nt] = __builtin_amdgcn_mfma_f32_16x16x32_bf16(al[mt], bh[nt], acc[mt][nt], 0, 0, 0);
          }
        }
    }
    __syncthreads();
  }
#pragma unroll
  for (int mt = 0; mt < 2; ++mt) {
#pragma unroll
    for (int nt = 0; nt < 2; ++nt) {
#pragma unroll
      for (int r = 0; r < 4; ++r) {
        int m = bm + wm * 32 + mt * 16 + g * 4 + r;   // row (token)
        int n = bn + wn * 32 + nt * 16 + c;           // col (dh / N)
        float val = acc[mt][nt][r] * alpha;
        if constexpr (MODE == 0) {
          bfpair pr = split2(val);
          Ch[(size_t)m * ldc + n] = pr.hi;
          Cl[(size_t)m * ldc + n] = pr.lo;
        } else if constexpr (MODE == 3) {
          Cf[(size_t)m * ldc + n] = val;
        } else if constexpr (MODE == 4) {
          size_t off = (((size_t)(m >> 5) * 4 + (n >> 4)) * 64 +
                        ((m & 31) + 32 * ((n >> 3) & 1))) * 8 + (n & 7);
          bfpair pr = split2(val);
          Ch[off] = pr.hi;
          Cl[off] = pr.lo;
        } else {  // MODE 5
          size_t off = ((((size_t)(m >> 5) * 2 + (n >> 5)) * 2 + ((m >> 4) & 1)) * 64 +
                        ((n & 31) + 32 * ((m >> 3) & 1))) * 8 + (m & 7);
          Ch[off] = f2bf(val);
        }
      }
    }
  }
}

// ---------------- flash MQA attention v8 (r14): packed + single-acc + split-KV x4 --
// grid (S/128, H, B*NSPL), 256 thr = 4 waves; wave w owns 32 q-rows; kv range = S/4.
__global__ __launch_bounds__(256) void mqa_attn(
    const short* __restrict__ qph, const short* __restrict__ qpl,
    const short* __restrict__ pkh, const short* __restrict__ pkl,
    const short* __restrict__ pv, short* __restrict__ pO, float* __restrict__ pML) {
  const int tid = threadIdx.x;
  const int lane = tid & 63, w = tid >> 6;
  const int j = lane & 31, b5 = lane >> 5;
  const int qt = blockIdx.x, h = blockIdx.y;
  const int b = blockIdx.z >> 2, sp = blockIdx.z & 3;
  const int q0 = qt * 128 + w * 32;
  const int kvbeg = sp * (S_ / NSPL), kvend = kvbeg + S_ / NSPL;

  const size_t qbase = (size_t)(b * S_ + q0 + j) * D_ + h * DH_ + b5 * 8;
  bf16x8 qh[4], ql[4];
#pragma unroll
  for (int m = 0; m < 4; ++m) {
    qh[m] = *(const bf16x8*)(qph + qbase + m * 16);
    ql[m] = *(const bf16x8*)(qpl + qbase + m * 16);
  }

  float mrow = -1.0e30f, lrow = 0.f;
  f32x16 o0 = {}, o1 = {};

  for (int kv0 = kvbeg; kv0 < kvend; kv0 += 32) {
    const size_t tg = (size_t)((b * S_ + kv0) >> 5);
    const short* kb = pkh + tg * 2048 + lane * 8;
    const short* kb2 = pkl + tg * 2048 + lane * 8;
    bf16x8 kh[4], kl[4];
#pragma unroll
    for (int m = 0; m < 4; ++m) {
      kh[m] = *(const bf16x8*)(kb + m * 512);
      kl[m] = *(const bf16x8*)(kb2 + m * 512);
    }
    f32x16 s = {};
#pragma unroll
    for (int m = 0; m < 4; ++m)
      s = __builtin_amdgcn_mfma_f32_32x32x16_bf16(kh[m], qh[m], s, 0, 0, 0);
#pragma unroll
    for (int m = 0; m < 4; ++m)
      s = __builtin_amdgcn_mfma_f32_32x32x16_bf16(kl[m], qh[m], s, 0, 0, 0);
#pragma unroll
    for (int m = 0; m < 4; ++m)
      s = __builtin_amdgcn_mfma_f32_32x32x16_bf16(kh[m], ql[m], s, 0, 0, 0);
    float mx = s[0];
#pragma unroll
    for (int r = 1; r < 16; ++r) mx = fmaxf(mx, s[r]);
    mx = fmaxf(mx, __shfl_xor(mx, 32));
    if (!__all(mx - mrow <= 8.0f)) {
      float mn = fmaxf(mrow, mx);
      float scale = exp2f(mrow - mn);
      mrow = mn;
      lrow *= scale;
      o0 *= scale;
      o1 *= scale;
    }
    float p[16];
#pragma unroll
    for (int r = 0; r < 16; ++r) p[r] = exp2f(s[r] - mrow);
    float rs = (((p[0] + p[1]) + (p[2] + p[3])) + ((p[4] + p[5]) + (p[6] + p[7]))) +
               (((p[8] + p[9]) + (p[10] + p[11])) + ((p[12] + p[13]) + (p[14] + p[15])));
    rs += __shfl_xor(rs, 32);
    lrow += rs;
    auto r0 = __builtin_amdgcn_permlane32_swap(cvtpk(p[0], p[1]),   cvtpk(p[4], p[5]),   false, false);
    auto r1 = __builtin_amdgcn_permlane32_swap(cvtpk(p[2], p[3]),   cvtpk(p[6], p[7]),   false, false);
    auto r2 = __builtin_amdgcn_permlane32_swap(cvtpk(p[8], p[9]),   cvtpk(p[12], p[13]), false, false);
    auto r3 = __builtin_amdgcn_permlane32_swap(cvtpk(p[10], p[11]), cvtpk(p[14], p[15]), false, false);
    union { uint4v u; bf16x8 v; } pa0, pa1;
    pa0.u = (uint4v){r0[0], r1[0], r0[1], r1[1]};  // kv 0..15 (per b5 half)
    pa1.u = (uint4v){r2[0], r3[0], r2[1], r3[1]};  // kv 16..31
    const short* vbp = pv + tg * 2048 + lane * 8;
    bf16x8 va00 = *(const bf16x8*)(vbp);
    bf16x8 va01 = *(const bf16x8*)(vbp + 512);
    bf16x8 va10 = *(const bf16x8*)(vbp + 1024);
    bf16x8 va11 = *(const bf16x8*)(vbp + 1536);
    o0 = __builtin_amdgcn_mfma_f32_32x32x16_bf16(va00, pa0.v, o0, 0, 0, 0);
    o0 = __builtin_amdgcn_mfma_f32_32x32x16_bf16(va01, pa1.v, o0, 0, 0, 0);
    o1 = __builtin_amdgcn_mfma_f32_32x32x16_bf16(va10, pa0.v, o1, 0, 0, 0);
    o1 = __builtin_amdgcn_mfma_f32_32x32x16_bf16(va11, pa1.v, o1, 0, 0, 0);
  }
  const size_t tok = (size_t)(b * S_ + q0 + j);
  const size_t obase = ((size_t)sp * MTOT + tok) * D_ + h * DH_;
#pragma unroll
  for (int r = 0; r < 16; ++r) {
    int dh0 = (r & 3) + 8 * (r >> 2) + 4 * b5;
    pO[obase + dh0] = f2bf(o0[r]);
    pO[obase + 32 + dh0] = f2bf(o1[r]);
  }
  if (b5 == 0) {
    size_t mb = (((size_t)sp * MTOT + tok) * H_ + h) * 2;
    pML[mb] = mrow;
    pML[mb + 1] = lrow;
  }
}

// ---------------- merge NSPL KV-split partials -> single bf16 ao ----------------
__global__ __launch_bounds__(256) void attn_merge(
    const short* __restrict__ pO, const float* __restrict__ pML,
    short* __restrict__ ao) {
  int qd = blockIdx.x * 256 + threadIdx.x;
  size_t idx = (size_t)qd * 4;
  int tok = (int)(idx >> 10);
  int h = (int)((idx >> 6) & 15);
  float ms[NSPL], ls[NSPL], mm = -1.0e30f;
#pragma unroll
  for (int s = 0; s < NSPL; ++s) {
    size_t mb = (((size_t)s * MTOT + tok) * H_ + h) * 2;
    ms[s] = pML[mb];
    ls[s] = pML[mb + 1];
    mm = fmaxf(mm, ms[s]);
  }
  float num[4] = {}, den = 0.f;
#pragma unroll
  for (int s = 0; s < NSPL; ++s) {
    float e = exp2f(ms[s] - mm);
    den += ls[s] * e;
    short4v o4 = *(const short4v*)(pO + (size_t)s * MTOT * D_ + idx);
    num[0] += bf2f(o4.x) * e;
    num[1] += bf2f(o4.y) * e;
    num[2] += bf2f(o4.z) * e;
    num[3] += bf2f(o4.w) * e;
  }
  float inv = 1.0f / den;
  short4v y;
  y.x = f2bf(num[0] * inv);
  y.y = f2bf(num[1] * inv);
  y.z = f2bf(num[2] * inv);
  y.w = f2bf(num[3] * inv);
  *(short4v*)(ao + idx) = y;
}

// ---------------- launch ----------------
extern "C" void kernel_launch(void* const* d_in, const int* in_sizes, int n_in,
                              void* d_out, int out_size, void* d_ws, size_t ws_size,
                              hipStream_t stream) {
  const float* q  = (const float*)d_in[0];
  const float* k  = (const float*)d_in[1];
  const float* v  = (const float*)d_in[2];
  const float* wq = (const float*)d_in[3];
  const float* wk = (const float*)d_in[4];
  const float* wv = (const float*)d_in[5];
  const float* wo = (const float*)d_in[6];

  short* p = (short*)d_ws;
  short* qhi = p; p += 4194304;   // dead after Q-proj -> pO splits 0,1
  short* qlo = p; p += 4194304;
  short* khi = p; p += 4194304;   // dead after K-proj -> pO splits 2,3
  short* klo = p; p += 4194304;
  short* vb  = p; p += 4194304;   // dead after V-proj -> pML
  short* wqh = p; p += 1048576;
  short* wql = p; p += 1048576;
  short* wkh = p; p += 65536;
  short* wkl = p; p += 65536;
  short* wvb = p; p += 65536;
  short* wob = p; p += 1048576;
  short* qph = p; p += 4194304;   // dead after attn -> ao
  short* qpl = p; p += 4194304;
  short* pkh = p; p += 524288;    // packed K hi [128 tiles][4][64][8]
  short* pkl = p; p += 524288;    // packed K lo
  short* pv  = p; p += 524288;    // packed V^T [128 tiles][2][2][64][8]
  short* pO  = qhi;               // [NSPL][4096][1024] bf16 = 33.6 MB
  float* pML = (float*)vb;        // [NSPL][4096][16][2] f32 = 2 MB
  short* ao  = qph;               // merge runs after attn reads qph/qpl

  cvt_split<<<dim3(2048), dim3(256), 0, stream>>>(q, k, v, wq, wk, wv, wo,
      qhi, qlo, khi, klo, vb, wqh, wql, wkh, wkl, wvb, wob);
  // qp = q @ wq^T * (0.125 * log2e)  -> exp2-domain scores
  gemm3<3, 0><<<dim3(64, 16), dim3(256), 0, stream>>>(qhi, qlo, wqh, wql, qph, qpl,
      nullptr, 1024, 1024, 1024, 1024, 0.125f * 1.44269504f);
  // kp -> packed fragment layout (split)
  gemm3<3, 4><<<dim3(64, 1), dim3(256), 0, stream>>>(khi, klo, wkh, wkl, pkh, pkl,
      nullptr, 1024, 1024, 1024, 64, 1.0f);
  // vp -> packed V^T fragment layout
  gemm3<1, 5><<<dim3(64, 1), dim3(256), 0, stream>>>(vb, nullptr, wvb, nullptr, pv,
      nullptr, nullptr, 1024, 1024, 1024, 64, 1.0f);
  mqa_attn<<<dim3(S_ / 128, 16, B_ * NSPL), dim3(256), 0, stream>>>(
      qph, qpl, pkh, pkl, pv, pO, pML);
  attn_merge<<<dim3(MTOT * D_ / 4 / 256), dim3(256), 0, stream>>>(pO, pML, ao);
  // d_out(f32) = ao @ wo^T  (single bf16 — post-softmax path tolerates it)
  gemm3<1, 3><<<dim3(64, 16), dim3(256), 0, stream>>>(ao, nullptr, wob, nullptr,
      nullptr, nullptr, (float*)d_out, 1024, 1024, 1024, 1024, 1.0f);
}